// Round 17
// baseline (760.025 us; speedup 1.0000x reference)
//
#include <hip/hip_runtime.h>
#include <hip/hip_bf16.h>

#define B_  32
#define LK  2048
#define DM  1024
#define NH  16

typedef __attribute__((ext_vector_type(8))) short short8;
typedef __attribute__((ext_vector_type(4))) float f32x4;

__device__ __forceinline__ ushort f2bf(float f){
  union { float f; unsigned u; } v; v.f = f;
  unsigned u = v.u;
  u += 0x7fffu + ((u >> 16) & 1u);   // RNE
  return (ushort)(u >> 16);
}

__device__ __forceinline__ short8 pack8(f32x4 a, f32x4 b){
  union { __hip_bfloat162 h[4]; short8 s; } r;
  r.h[0] = __float22bfloat162_rn(make_float2(a[0], a[1]));
  r.h[1] = __float22bfloat162_rn(make_float2(a[2], a[3]));
  r.h[2] = __float22bfloat162_rn(make_float2(b[0], b[1]));
  r.h[3] = __float22bfloat162_rn(make_float2(b[2], b[3]));
  return r.s;
}

__device__ __forceinline__ void gll16(const void* g, void* l){
  __builtin_amdgcn_global_load_lds(
      (__attribute__((address_space(1))) void*)g,
      (__attribute__((address_space(3))) void*)l, 16, 0, 0);
}

#define C2LOG2E 2.8853900817779268f  /* 2*log2(e) */

// ---- K0: prepass.
//  [0,1024):    Wk [k][n] f32 -> wkt [n][k] bf16 (transpose+convert)
//  [1024,1152): qup[b][n] = bq[n] + query[b,:] @ Wq[:,n]
//  [1152,1184): per-batch mask compaction: ascending idx of unmasked l, zero-padded
//               to 128-multiple, + cnt[b].
__global__ __launch_bounds__(256) void k_pre(const float* __restrict__ Wk, ushort* __restrict__ wkt,
                                             const float* __restrict__ query, const float* __restrict__ Wq,
                                             const float* __restrict__ bq, float* __restrict__ qup,
                                             const int* __restrict__ mask, int* __restrict__ idxv,
                                             int* __restrict__ cntv){
  __shared__ float smem[1056];
  int bid = blockIdx.x;
  int t = threadIdx.x;
  if (bid >= 1152){
    int bb = bid - 1152;                 // batch
    const int* m = mask + (size_t)bb * LK;
    int* idxb = idxv + (size_t)bb * LK;
    int* ps = (int*)smem;
    int keep[8]; int c8 = 0;
#pragma unroll
    for (int u = 0; u < 8; ++u){
      keep[u] = (m[t*8 + u] == 0);
      c8 += keep[u];
    }
    ps[t] = c8; __syncthreads();
    for (int off = 1; off < 256; off <<= 1){
      int v = (t >= off) ? ps[t - off] : 0;
      __syncthreads();
      ps[t] += v;
      __syncthreads();
    }
    int pos = ps[t] - c8;                // exclusive prefix
    int tot = ps[255];
#pragma unroll
    for (int u = 0; u < 8; ++u){
      if (keep[u]) idxb[pos++] = t*8 + u;
    }
    int pad = ((tot + 127) >> 7) << 7;
    for (int p = tot + t; p < pad; p += 256) idxb[p] = 0;  // pad rows (stores masked out)
    if (t == 0) cntv[bb] = tot;
  } else if (bid < 1024){
    float (*tile)[33] = (float(*)[33])smem;
    int n0 = (bid & 31) * 32, k0 = (bid >> 5) * 32;
    int tx = t & 31, ty = t >> 5;
#pragma unroll
    for (int r = 0; r < 4; ++r)
      tile[ty + 8*r][tx] = Wk[(size_t)(k0 + ty + 8*r) * DM + n0 + tx];
    __syncthreads();
#pragma unroll
    for (int r = 0; r < 4; ++r){
      int n = ty + 8*r;
      wkt[(size_t)(n0 + n) * DM + k0 + tx] = f2bf(tile[tx][n]);
    }
  } else {
    int bb = bid - 1024;
    int b = bb >> 2, nc = bb & 3;
    float* q = smem;
#pragma unroll
    for (int j = 0; j < 4; ++j) q[j*256 + t] = query[(size_t)b*DM + j*256 + t];
    __syncthreads();
    int n = nc*256 + t;
    float acc = bq[n];
#pragma unroll 16
    for (int k = 0; k < DM; ++k) acc += q[k] * Wq[(size_t)k*DM + n];
    qup[(size_t)b*DM + n] = acc;
  }
}

// ---- K2 v17: v15 with SINGLE B buffer (B-dbuf was measured null, R14) ->
// 48 KB LDS -> 3 blocks/CU -> 768 slots -> ceil(1088/768)=2 dispatch rounds
// (was 3 rounds on 512 slots). 12 waves/CU hides the phase-1 B-drain (m114).
__global__ __launch_bounds__(256, 3) void k_gemm(
    const float* __restrict__ key, const ushort* __restrict__ wkt,
    const float* __restrict__ qup, const float* __restrict__ bk,
    const float* __restrict__ wsc, float* __restrict__ scores,
    const int* __restrict__ idxv, const int* __restrict__ cntv)
{
  __shared__ ushort ldsA[128*64];      // 16 KB (swizzled image)
  __shared__ ushort ldsB[256*64];      // 32 KB
  const int tid  = threadIdx.x;
  const int lane = tid & 63;
  const int wc   = tid >> 6;           // wave = col group 0..3 (one head each)
  const int l15  = lane & 15, l16 = lane >> 4;

  const int bid = blockIdx.x;          // grid 2048
  const int xcd = bid & 7;
  const int j   = bid >> 3;            // 0..255
  const int ct4 = j & 3;               // 256-col tile (4 heads)
  const int rb  = xcd * 64 + (j >> 2); // row panel 0..511
  const int b     = rb >> 4;
  const int panel = rb & 15;

  const int cnt = cntv[b];
  if (panel * 128 >= cnt) return;      // compacted panel count ~8-9 of 16
  const int* idxb = idxv + (size_t)b * LK;

  const int rlo = tid >> 3;            // 0..31
  const int g8  = rlo & 7;
  const int sk8 = (tid & 7) ^ g8;      // involution: source slot == written-image slot
  const ushort* bbase = wkt + ((size_t)ct4*256 + rlo) * DM + sk8*8;

  const float* akey[4];
#pragma unroll
  for (int c = 0; c < 4; ++c){
    int rowc = panel*128 + rlo + c*32;
    akey[c] = key + ((size_t)b * LK + idxb[rowc]) * DM + sk8*8;
  }

  float qbc[4], wm2[4], wsum = 0.f;
#pragma unroll
  for (int ni = 0; ni < 4; ++ni){
    int n = ct4*256 + wc*64 + ni*16 + l15;
    float w = wsc[ni*16 + l15];
    qbc[ni] = (qup[(size_t)b*DM + n] + bk[n]) * C2LOG2E;
    wm2[ni] = -2.f * w;
    wsum   += w;
  }

  f32x4 acc[8][4];
#pragma unroll
  for (int mi = 0; mi < 8; ++mi)
#pragma unroll
    for (int ni = 0; ni < 4; ++ni) acc[mi][ni] = (f32x4){0.f,0.f,0.f,0.f};

  const int sw = (l15 & 7) << 4;       // read-side XOR (row&7)<<4

  // prologue: A(0) -> pack -> sa
  short8 sa[4];
#pragma unroll
  for (int c = 0; c < 4; ++c){
    const float* ap = akey[c];
    f32x4 x0 = *(const f32x4*)ap, x1 = *(const f32x4*)(ap + 4);
    sa[c] = pack8(x0, x1);
  }

  for (int kt = 0; kt < 16; ++kt){
    // phase 1: ds_write A(kt) image + gll B(kt); drain; barrier
#pragma unroll
    for (int c = 0; c < 4; ++c)
      *(short8*)((char*)ldsA + (c*256 + tid)*16) = sa[c];
#pragma unroll
    for (int c = 0; c < 8; ++c)
      gll16(bbase + (size_t)kt*64 + (size_t)c*32*DM, (char*)ldsB + (c*256 + tid)*16);
    asm volatile("s_waitcnt vmcnt(0) lgkmcnt(0)" ::: "memory");
    __builtin_amdgcn_s_barrier();
    asm volatile("" ::: "memory");

    // phase 2: issue A(kt+1) f32 loads (hide under MFMA), frags + 64 MFMA, pack
    f32x4 a0[4], a1[4];
    if (kt < 15){
#pragma unroll
      for (int c = 0; c < 4; ++c){
        const float* ap = akey[c] + (kt+1)*64;
        a0[c] = *(const f32x4*)ap; a1[c] = *(const f32x4*)(ap + 4);
      }
    }

#pragma unroll
    for (int kk = 0; kk < 2; ++kk){
      short8 af[8], bfr[4];
#pragma unroll
      for (int mi = 0; mi < 8; ++mi){
        int row = mi*16 + l15;
        af[mi] = *(const short8*)((const char*)ldsA + row*128 + ((kk*64 + l16*16) ^ sw));
      }
#pragma unroll
      for (int ni = 0; ni < 4; ++ni){
        int col = wc*64 + ni*16 + l15;
        bfr[ni] = *(const short8*)((const char*)ldsB + col*128 + ((kk*64 + l16*16) ^ sw));
      }
      __builtin_amdgcn_s_setprio(1);
#pragma unroll
      for (int mi = 0; mi < 8; ++mi)
#pragma unroll
        for (int ni = 0; ni < 4; ++ni)
          acc[mi][ni] = __builtin_amdgcn_mfma_f32_16x16x32_bf16(af[mi], bfr[ni], acc[mi][ni], 0, 0, 0);
      __builtin_amdgcn_s_setprio(0);
    }

    if (kt < 15){
#pragma unroll
      for (int c = 0; c < 4; ++c)
        sa[c] = pack8(a0[c], a1[c]);   // consumes A loads; only sa crosses barrier
    }
    __builtin_amdgcn_s_barrier();      // raw: all waves done READING images
    asm volatile("" ::: "memory");
  }

  // epilogue: scatter scores[b,h, idx[rowc]] = sum_col w*tanh(acc + q + bk)
  const size_t srow = (size_t)(b*NH + ct4*4 + wc) * LK;
#pragma unroll
  for (int mi = 0; mi < 8; ++mi){
    f32x4 s = {wsum, wsum, wsum, wsum};
#pragma unroll
    for (int ni = 0; ni < 4; ++ni)
#pragma unroll
      for (int r = 0; r < 4; ++r){
        float a  = fmaf(acc[mi][ni][r], C2LOG2E, qbc[ni]);
        float e  = __builtin_amdgcn_exp2f(a);
        float rc = __builtin_amdgcn_rcpf(e + 1.f);
        s[r] = fmaf(wm2[ni], rc, s[r]);
      }
#pragma unroll
    for (int r = 0; r < 4; ++r){
      float v = s[r];
      v += __shfl_xor(v, 1);
      v += __shfl_xor(v, 2);
      v += __shfl_xor(v, 4);
      v += __shfl_xor(v, 8);
      s[r] = v;
    }
    if (l15 == 0){
      int rowc0 = panel*128 + mi*16 + l16*4;
#pragma unroll
      for (int r = 0; r < 4; ++r){
        int rowc = rowc0 + r;
        if (rowc < cnt) scores[srow + idxb[rowc]] = s[r];
      }
    }
  }
}

// ---- K3 fused: masked softmax (attn output) + compacted context slice.
__global__ __launch_bounds__(256) void k_smctx(const float* __restrict__ scr, const int* __restrict__ mask,
                                               const float* __restrict__ value, float* __restrict__ attn,
                                               float* __restrict__ ctxbuf,
                                               const int* __restrict__ idxv, const int* __restrict__ cntv){
  __shared__ float red[8];
  __shared__ float sm[LK];
  const int bh = blockIdx.x;
  const int b = bh >> 4, h = bh & 15;
  const float* s = scr + (size_t)bh * LK;
  const int*   m = mask + (size_t)b * LK;
  float*       a = attn + (size_t)bh * LK;
  const int t = threadIdx.x;

  float sv[8]; int mv[8];
  float lmax = -1e30f;
#pragma unroll
  for (int j = 0; j < 8; ++j){
    int i = j*256 + t;
    sv[j] = s[i]; mv[j] = m[i];
    if (!mv[j]) lmax = fmaxf(lmax, sv[j]);
  }
#pragma unroll
  for (int off = 32; off >= 1; off >>= 1) lmax = fmaxf(lmax, __shfl_xor(lmax, off));
  if ((t & 63) == 0) red[t >> 6] = lmax;
  __syncthreads();
  lmax = fmaxf(fmaxf(red[0], red[1]), fmaxf(red[2], red[3]));

  float ev[8]; float lsum = 0.f;
#pragma unroll
  for (int j = 0; j < 8; ++j){
    ev[j] = mv[j] ? 0.f : __expf(sv[j] - lmax);
    lsum += ev[j];
  }
#pragma unroll
  for (int off = 32; off >= 1; off >>= 1) lsum += __shfl_xor(lsum, off);
  if ((t & 63) == 0) red[4 + (t >> 6)] = lsum;
  __syncthreads();
  lsum = red[4] + red[5] + red[6] + red[7];
  float inv = 1.f / lsum;
#pragma unroll
  for (int j = 0; j < 8; ++j){
    float w = ev[j] * inv;
    a[j*256 + t]  = w;
    sm[j*256 + t] = w;
  }
  __syncthreads();

  // compacted ctx: group w = t>>5 handles rows [p0,p1) of the idx list;
  // col pair c2 = (t&31)*2 (float2 = 8 B/lane).
  const int cnt = cntv[b];
  const int* idxb = idxv + (size_t)b * LK;
  const int c2 = (t & 31) * 2, w = t >> 5;
  const int per = (cnt + 7) >> 3;
  const int p0 = w * per;
  const int p1 = min(p0 + per, cnt);
  const float* vbase = value + (size_t)b*LK*DM + h*64 + c2;
  float px = 0.f, py = 0.f;
#pragma unroll 2
  for (int p = p0; p < p1; ++p){
    int l = idxb[p];
    float wgt = sm[l];
    float2 v = *(const float2*)(vbase + (size_t)l*DM);
    px = fmaf(wgt, v.x, px); py = fmaf(wgt, v.y, py);
  }
  float2 tot = make_float2(px, py);
  __syncthreads();                 // all reads of sm done
  *(float2*)&sm[w*64 + c2] = tot;  // 8 partials per col
  __syncthreads();
  if (t < 64){
    float r = 0.f;
#pragma unroll
    for (int g = 0; g < 8; ++g) r += sm[g*64 + t];
    ctxbuf[(size_t)b*DM + h*64 + t] = r;
  }
}

// ---- K6: output = context @ Wf + bf (output #1)
__global__ __launch_bounds__(256) void k_out(const float* __restrict__ ctxbuf, const float* __restrict__ Wf,
                                             const float* __restrict__ bfv, float* __restrict__ out){
  __shared__ float ctx[DM];
  int b = blockIdx.x >> 2, nc = blockIdx.x & 3;
  int t = threadIdx.x;
#pragma unroll
  for (int j = 0; j < 4; ++j)
    ctx[j*256 + t] = ctxbuf[(size_t)b*DM + j*256 + t];
  __syncthreads();
  int n = nc*256 + t;
  float acc = bfv[n];
#pragma unroll 16
  for (int k = 0; k < DM; ++k) acc += ctx[k] * Wf[(size_t)k*DM + n];
  out[(size_t)b*DM + n] = acc;
}

extern "C" void kernel_launch(void* const* d_in, const int* in_sizes, int n_in,
                              void* d_out, int out_size, void* d_ws, size_t ws_size,
                              hipStream_t stream){
  (void)in_sizes; (void)n_in; (void)out_size; (void)ws_size;
  const float* key   = (const float*)d_in[0];
  const float* value = (const float*)d_in[1];
  const float* query = (const float*)d_in[2];
  const int*   mask  = (const int*)d_in[3];
  const float* Wk    = (const float*)d_in[4];
  const float* bk    = (const float*)d_in[5];
  const float* Wq    = (const float*)d_in[6];
  const float* bq    = (const float*)d_in[7];
  const float* wsc   = (const float*)d_in[8];
  // d_in[9] = b_score: softmax-invariant, unused
  const float* Wf    = (const float*)d_in[10];
  const float* bfv   = (const float*)d_in[11];

  float* out0 = (float*)d_out;
  float* attn = out0 + (size_t)B_ * DM;   // [B,H,1,Lk] region

  char* ws = (char*)d_ws;
  ushort* wkt  = (ushort*)(ws);                                       // 2 MB
  float*  qup  = (float*)(ws + (2u<<20));                             // 128 KB
  float*  scr  = (float*)(ws + (2u<<20) + (128u<<10));                // 4 MB
  float*  ctxb = (float*)(ws + (2u<<20) + (128u<<10) + (4u<<20));     // 128 KB
  int*    idxv = (int*)  (ws + (2u<<20) + (256u<<10) + (4u<<20));     // 256 KB
  int*    cntv = (int*)  (ws + (2u<<20) + (512u<<10) + (4u<<20));     // 128 B

  k_pre<<<1184, 256, 0, stream>>>(Wk, wkt, query, Wq, bq, qup, mask, idxv, cntv);
  k_gemm<<<2048, 256, 0, stream>>>(key, wkt, qup, bk, wsc, scr, idxv, cntv);
  k_smctx<<<512, 256, 0, stream>>>(scr, mask, value, attn, ctxb, idxv, cntv);
  k_out<<<128, 256, 0, stream>>>(ctxb, Wf, bfv, out0);
}

// Round 18
// 346.374 us; speedup vs baseline: 2.1942x; 2.1942x over previous
//
#include <hip/hip_runtime.h>
#include <hip/hip_bf16.h>

#define B_  32
#define LK  2048
#define DM  1024
#define NH  16

typedef __attribute__((ext_vector_type(8))) short short8;
typedef __attribute__((ext_vector_type(4))) float f32x4;

__device__ __forceinline__ ushort f2bf(float f){
  union { float f; unsigned u; } v; v.f = f;
  unsigned u = v.u;
  u += 0x7fffu + ((u >> 16) & 1u);   // RNE
  return (ushort)(u >> 16);
}

__device__ __forceinline__ short8 pack8(f32x4 a, f32x4 b){
  union { __hip_bfloat162 h[4]; short8 s; } r;
  r.h[0] = __float22bfloat162_rn(make_float2(a[0], a[1]));
  r.h[1] = __float22bfloat162_rn(make_float2(a[2], a[3]));
  r.h[2] = __float22bfloat162_rn(make_float2(b[0], b[1]));
  r.h[3] = __float22bfloat162_rn(make_float2(b[2], b[3]));
  return r.s;
}

__device__ __forceinline__ void gll16(const void* g, void* l){
  __builtin_amdgcn_global_load_lds(
      (__attribute__((address_space(1))) void*)g,
      (__attribute__((address_space(3))) void*)l, 16, 0, 0);
}

#define C2LOG2E 2.8853900817779268f  /* 2*log2(e) */

// ---- K0: prepass.
//  [0,1024):    Wk [k][n] f32 -> wkt [n][k] bf16 (transpose+convert)
//  [1024,1152): qup[b][n] = bq[n] + query[b,:] @ Wq[:,n]
//  [1152,1184): per-batch mask compaction: ascending idx of unmasked l, zero-padded
//               to 128-multiple, + cnt[b].
__global__ __launch_bounds__(256) void k_pre(const float* __restrict__ Wk, ushort* __restrict__ wkt,
                                             const float* __restrict__ query, const float* __restrict__ Wq,
                                             const float* __restrict__ bq, float* __restrict__ qup,
                                             const int* __restrict__ mask, int* __restrict__ idxv,
                                             int* __restrict__ cntv){
  __shared__ float smem[1056];
  int bid = blockIdx.x;
  int t = threadIdx.x;
  if (bid >= 1152){
    int bb = bid - 1152;                 // batch
    const int* m = mask + (size_t)bb * LK;
    int* idxb = idxv + (size_t)bb * LK;
    int* ps = (int*)smem;
    int keep[8]; int c8 = 0;
#pragma unroll
    for (int u = 0; u < 8; ++u){
      keep[u] = (m[t*8 + u] == 0);
      c8 += keep[u];
    }
    ps[t] = c8; __syncthreads();
    for (int off = 1; off < 256; off <<= 1){
      int v = (t >= off) ? ps[t - off] : 0;
      __syncthreads();
      ps[t] += v;
      __syncthreads();
    }
    int pos = ps[t] - c8;                // exclusive prefix
    int tot = ps[255];
#pragma unroll
    for (int u = 0; u < 8; ++u){
      if (keep[u]) idxb[pos++] = t*8 + u;
    }
    int pad = ((tot + 127) >> 7) << 7;
    for (int p = tot + t; p < pad; p += 256) idxb[p] = 0;  // pad rows (stores masked out)
    if (t == 0) cntv[bb] = tot;
  } else if (bid < 1024){
    float (*tile)[33] = (float(*)[33])smem;
    int n0 = (bid & 31) * 32, k0 = (bid >> 5) * 32;
    int tx = t & 31, ty = t >> 5;
#pragma unroll
    for (int r = 0; r < 4; ++r)
      tile[ty + 8*r][tx] = Wk[(size_t)(k0 + ty + 8*r) * DM + n0 + tx];
    __syncthreads();
#pragma unroll
    for (int r = 0; r < 4; ++r){
      int n = ty + 8*r;
      wkt[(size_t)(n0 + n) * DM + k0 + tx] = f2bf(tile[tx][n]);
    }
  } else {
    int bb = bid - 1024;
    int b = bb >> 2, nc = bb & 3;
    float* q = smem;
#pragma unroll
    for (int j = 0; j < 4; ++j) q[j*256 + t] = query[(size_t)b*DM + j*256 + t];
    __syncthreads();
    int n = nc*256 + t;
    float acc = bq[n];
#pragma unroll 16
    for (int k = 0; k < DM; ++k) acc += q[k] * Wq[(size_t)k*DM + n];
    qup[(size_t)b*DM + n] = acc;
  }
}

// ---- K2 v18: v15 structure, SINGLE B buffer (dbuf proven null, R14) at
// __launch_bounds__(256,4): budget = 512/4 = 128 VGPR — exactly what R16's kernel
// measured (VGPR_Count=128, no spill). 48 KB LDS -> 3 blocks/CU (LDS-capped) ->
// 768 slots -> ceil(1088/768) = 2 dispatch rounds (was 3). B-latency at phase-1
// drain is covered by 12 waves/CU TLP (m114; R8 regime).
__global__ __launch_bounds__(256, 4) void k_gemm(
    const float* __restrict__ key, const ushort* __restrict__ wkt,
    const float* __restrict__ qup, const float* __restrict__ bk,
    const float* __restrict__ wsc, float* __restrict__ scores,
    const int* __restrict__ idxv, const int* __restrict__ cntv)
{
  __shared__ ushort ldsA[128*64];      // 16 KB (swizzled image)
  __shared__ ushort ldsB[256*64];      // 32 KB
  const int tid  = threadIdx.x;
  const int lane = tid & 63;
  const int wc   = tid >> 6;           // wave = col group 0..3 (one head each)
  const int l15  = lane & 15, l16 = lane >> 4;

  const int bid = blockIdx.x;          // grid 2048
  const int xcd = bid & 7;
  const int j   = bid >> 3;            // 0..255
  const int ct4 = j & 3;               // 256-col tile (4 heads)
  const int rb  = xcd * 64 + (j >> 2); // row panel 0..511
  const int b     = rb >> 4;
  const int panel = rb & 15;

  const int cnt = cntv[b];
  if (panel * 128 >= cnt) return;      // compacted panel count ~8-9 of 16
  const int* idxb = idxv + (size_t)b * LK;

  const int rlo = tid >> 3;            // 0..31
  const int g8  = rlo & 7;
  const int sk8 = (tid & 7) ^ g8;      // involution: source slot == written-image slot
  const ushort* bbase = wkt + ((size_t)ct4*256 + rlo) * DM + sk8*8;

  const float* akey[4];
#pragma unroll
  for (int c = 0; c < 4; ++c){
    int rowc = panel*128 + rlo + c*32;
    akey[c] = key + ((size_t)b * LK + idxb[rowc]) * DM + sk8*8;
  }

  float qbc[4], wm2[4], wsum = 0.f;
#pragma unroll
  for (int ni = 0; ni < 4; ++ni){
    int n = ct4*256 + wc*64 + ni*16 + l15;
    float w = wsc[ni*16 + l15];
    qbc[ni] = (qup[(size_t)b*DM + n] + bk[n]) * C2LOG2E;
    wm2[ni] = -2.f * w;
    wsum   += w;
  }

  f32x4 acc[8][4];
#pragma unroll
  for (int mi = 0; mi < 8; ++mi)
#pragma unroll
    for (int ni = 0; ni < 4; ++ni) acc[mi][ni] = (f32x4){0.f,0.f,0.f,0.f};

  const int sw = (l15 & 7) << 4;       // read-side XOR (row&7)<<4

  // prologue: A(0) -> pack -> sa
  short8 sa[4];
#pragma unroll
  for (int c = 0; c < 4; ++c){
    const float* ap = akey[c];
    f32x4 x0 = *(const f32x4*)ap, x1 = *(const f32x4*)(ap + 4);
    sa[c] = pack8(x0, x1);
  }

  for (int kt = 0; kt < 16; ++kt){
    // phase 1: ds_write A(kt) image + gll B(kt); drain; barrier
#pragma unroll
    for (int c = 0; c < 4; ++c)
      *(short8*)((char*)ldsA + (c*256 + tid)*16) = sa[c];
#pragma unroll
    for (int c = 0; c < 8; ++c)
      gll16(bbase + (size_t)kt*64 + (size_t)c*32*DM, (char*)ldsB + (c*256 + tid)*16);
    asm volatile("s_waitcnt vmcnt(0) lgkmcnt(0)" ::: "memory");
    __builtin_amdgcn_s_barrier();
    asm volatile("" ::: "memory");

    // phase 2: issue A(kt+1) f32 loads (hide under MFMA), frags + 64 MFMA, pack
    f32x4 a0[4], a1[4];
    if (kt < 15){
#pragma unroll
      for (int c = 0; c < 4; ++c){
        const float* ap = akey[c] + (kt+1)*64;
        a0[c] = *(const f32x4*)ap; a1[c] = *(const f32x4*)(ap + 4);
      }
    }

#pragma unroll
    for (int kk = 0; kk < 2; ++kk){
      short8 af[8], bfr[4];
#pragma unroll
      for (int mi = 0; mi < 8; ++mi){
        int row = mi*16 + l15;
        af[mi] = *(const short8*)((const char*)ldsA + row*128 + ((kk*64 + l16*16) ^ sw));
      }
#pragma unroll
      for (int ni = 0; ni < 4; ++ni){
        int col = wc*64 + ni*16 + l15;
        bfr[ni] = *(const short8*)((const char*)ldsB + col*128 + ((kk*64 + l16*16) ^ sw));
      }
      __builtin_amdgcn_s_setprio(1);
#pragma unroll
      for (int mi = 0; mi < 8; ++mi)
#pragma unroll
        for (int ni = 0; ni < 4; ++ni)
          acc[mi][ni] = __builtin_amdgcn_mfma_f32_16x16x32_bf16(af[mi], bfr[ni], acc[mi][ni], 0, 0, 0);
      __builtin_amdgcn_s_setprio(0);
    }

    if (kt < 15){
#pragma unroll
      for (int c = 0; c < 4; ++c)
        sa[c] = pack8(a0[c], a1[c]);   // consumes A loads; only sa crosses barrier
    }
    __builtin_amdgcn_s_barrier();      // raw: all waves done READING images
    asm volatile("" ::: "memory");
  }

  // epilogue: scatter scores[b,h, idx[rowc]] = sum_col w*tanh(acc + q + bk)
  const size_t srow = (size_t)(b*NH + ct4*4 + wc) * LK;
#pragma unroll
  for (int mi = 0; mi < 8; ++mi){
    f32x4 s = {wsum, wsum, wsum, wsum};
#pragma unroll
    for (int ni = 0; ni < 4; ++ni)
#pragma unroll
      for (int r = 0; r < 4; ++r){
        float a  = fmaf(acc[mi][ni][r], C2LOG2E, qbc[ni]);
        float e  = __builtin_amdgcn_exp2f(a);
        float rc = __builtin_amdgcn_rcpf(e + 1.f);
        s[r] = fmaf(wm2[ni], rc, s[r]);
      }
#pragma unroll
    for (int r = 0; r < 4; ++r){
      float v = s[r];
      v += __shfl_xor(v, 1);
      v += __shfl_xor(v, 2);
      v += __shfl_xor(v, 4);
      v += __shfl_xor(v, 8);
      s[r] = v;
    }
    if (l15 == 0){
      int rowc0 = panel*128 + mi*16 + l16*4;
#pragma unroll
      for (int r = 0; r < 4; ++r){
        int rowc = rowc0 + r;
        if (rowc < cnt) scores[srow + idxb[rowc]] = s[r];
      }
    }
  }
}

// ---- K3 fused: masked softmax (attn output) + compacted context slice.
__global__ __launch_bounds__(256) void k_smctx(const float* __restrict__ scr, const int* __restrict__ mask,
                                               const float* __restrict__ value, float* __restrict__ attn,
                                               float* __restrict__ ctxbuf,
                                               const int* __restrict__ idxv, const int* __restrict__ cntv){
  __shared__ float red[8];
  __shared__ float sm[LK];
  const int bh = blockIdx.x;
  const int b = bh >> 4, h = bh & 15;
  const float* s = scr + (size_t)bh * LK;
  const int*   m = mask + (size_t)b * LK;
  float*       a = attn + (size_t)bh * LK;
  const int t = threadIdx.x;

  float sv[8]; int mv[8];
  float lmax = -1e30f;
#pragma unroll
  for (int j = 0; j < 8; ++j){
    int i = j*256 + t;
    sv[j] = s[i]; mv[j] = m[i];
    if (!mv[j]) lmax = fmaxf(lmax, sv[j]);
  }
#pragma unroll
  for (int off = 32; off >= 1; off >>= 1) lmax = fmaxf(lmax, __shfl_xor(lmax, off));
  if ((t & 63) == 0) red[t >> 6] = lmax;
  __syncthreads();
  lmax = fmaxf(fmaxf(red[0], red[1]), fmaxf(red[2], red[3]));

  float ev[8]; float lsum = 0.f;
#pragma unroll
  for (int j = 0; j < 8; ++j){
    ev[j] = mv[j] ? 0.f : __expf(sv[j] - lmax);
    lsum += ev[j];
  }
#pragma unroll
  for (int off = 32; off >= 1; off >>= 1) lsum += __shfl_xor(lsum, off);
  if ((t & 63) == 0) red[4 + (t >> 6)] = lsum;
  __syncthreads();
  lsum = red[4] + red[5] + red[6] + red[7];
  float inv = 1.f / lsum;
#pragma unroll
  for (int j = 0; j < 8; ++j){
    float w = ev[j] * inv;
    a[j*256 + t]  = w;
    sm[j*256 + t] = w;
  }
  __syncthreads();

  // compacted ctx: group w = t>>5 handles rows [p0,p1) of the idx list;
  // col pair c2 = (t&31)*2 (float2 = 8 B/lane).
  const int cnt = cntv[b];
  const int* idxb = idxv + (size_t)b * LK;
  const int c2 = (t & 31) * 2, w = t >> 5;
  const int per = (cnt + 7) >> 3;
  const int p0 = w * per;
  const int p1 = min(p0 + per, cnt);
  const float* vbase = value + (size_t)b*LK*DM + h*64 + c2;
  float px = 0.f, py = 0.f;
#pragma unroll 2
  for (int p = p0; p < p1; ++p){
    int l = idxb[p];
    float wgt = sm[l];
    float2 v = *(const float2*)(vbase + (size_t)l*DM);
    px = fmaf(wgt, v.x, px); py = fmaf(wgt, v.y, py);
  }
  float2 tot = make_float2(px, py);
  __syncthreads();                 // all reads of sm done
  *(float2*)&sm[w*64 + c2] = tot;  // 8 partials per col
  __syncthreads();
  if (t < 64){
    float r = 0.f;
#pragma unroll
    for (int g = 0; g < 8; ++g) r += sm[g*64 + t];
    ctxbuf[(size_t)b*DM + h*64 + t] = r;
  }
}

// ---- K6: output = context @ Wf + bf (output #1)
__global__ __launch_bounds__(256) void k_out(const float* __restrict__ ctxbuf, const float* __restrict__ Wf,
                                             const float* __restrict__ bfv, float* __restrict__ out){
  __shared__ float ctx[DM];
  int b = blockIdx.x >> 2, nc = blockIdx.x & 3;
  int t = threadIdx.x;
#pragma unroll
  for (int j = 0; j < 4; ++j)
    ctx[j*256 + t] = ctxbuf[(size_t)b*DM + j*256 + t];
  __syncthreads();
  int n = nc*256 + t;
  float acc = bfv[n];
#pragma unroll 16
  for (int k = 0; k < DM; ++k) acc += ctx[k] * Wf[(size_t)k*DM + n];
  out[(size_t)b*DM + n] = acc;
}

extern "C" void kernel_launch(void* const* d_in, const int* in_sizes, int n_in,
                              void* d_out, int out_size, void* d_ws, size_t ws_size,
                              hipStream_t stream){
  (void)in_sizes; (void)n_in; (void)out_size; (void)ws_size;
  const float* key   = (const float*)d_in[0];
  const float* value = (const float*)d_in[1];
  const float* query = (const float*)d_in[2];
  const int*   mask  = (const int*)d_in[3];
  const float* Wk    = (const float*)d_in[4];
  const float* bk    = (const float*)d_in[5];
  const float* Wq    = (const float*)d_in[6];
  const float* bq    = (const float*)d_in[7];
  const float* wsc   = (const float*)d_in[8];
  // d_in[9] = b_score: softmax-invariant, unused
  const float* Wf    = (const float*)d_in[10];
  const float* bfv   = (const float*)d_in[11];

  float* out0 = (float*)d_out;
  float* attn = out0 + (size_t)B_ * DM;   // [B,H,1,Lk] region

  char* ws = (char*)d_ws;
  ushort* wkt  = (ushort*)(ws);                                       // 2 MB
  float*  qup  = (float*)(ws + (2u<<20));                             // 128 KB
  float*  scr  = (float*)(ws + (2u<<20) + (128u<<10));                // 4 MB
  float*  ctxb = (float*)(ws + (2u<<20) + (128u<<10) + (4u<<20));     // 128 KB
  int*    idxv = (int*)  (ws + (2u<<20) + (256u<<10) + (4u<<20));     // 256 KB
  int*    cntv = (int*)  (ws + (2u<<20) + (512u<<10) + (4u<<20));     // 128 B

  k_pre<<<1184, 256, 0, stream>>>(Wk, wkt, query, Wq, bq, qup, mask, idxv, cntv);
  k_gemm<<<2048, 256, 0, stream>>>(key, wkt, qup, bk, wsc, scr, idxv, cntv);
  k_smctx<<<512, 256, 0, stream>>>(scr, mask, value, attn, ctxb, idxv, cntv);
  k_out<<<128, 256, 0, stream>>>(ctxb, Wf, bfv, out0);
}

// Round 19
// 232.659 us; speedup vs baseline: 3.2667x; 1.4888x over previous
//
#include <hip/hip_runtime.h>
#include <hip/hip_bf16.h>

#define B_  32
#define LK  2048
#define DM  1024
#define NH  16

typedef __attribute__((ext_vector_type(8))) short short8;
typedef __attribute__((ext_vector_type(4))) float f32x4;

__device__ __forceinline__ ushort f2bf(float f){
  union { float f; unsigned u; } v; v.f = f;
  unsigned u = v.u;
  u += 0x7fffu + ((u >> 16) & 1u);   // RNE
  return (ushort)(u >> 16);
}

__device__ __forceinline__ short8 pack8(f32x4 a, f32x4 b){
  union { __hip_bfloat162 h[4]; short8 s; } r;
  r.h[0] = __float22bfloat162_rn(make_float2(a[0], a[1]));
  r.h[1] = __float22bfloat162_rn(make_float2(a[2], a[3]));
  r.h[2] = __float22bfloat162_rn(make_float2(b[0], b[1]));
  r.h[3] = __float22bfloat162_rn(make_float2(b[2], b[3]));
  return r.s;
}

__device__ __forceinline__ void gll16(const void* g, void* l){
  __builtin_amdgcn_global_load_lds(
      (__attribute__((address_space(1))) void*)g,
      (__attribute__((address_space(3))) void*)l, 16, 0, 0);
}

#define C2LOG2E 2.8853900817779268f  /* 2*log2(e) */

// ---- K0: prepass.
//  [0,1024):    Wk [k][n] f32 -> wkt [n][k] bf16 (transpose+convert)
//  [1024,1152): qup[b][n] = bq[n] + query[b,:] @ Wq[:,n]
//  [1152,1184): per-batch mask compaction: ascending idx of unmasked l, zero-padded
//               to 128-multiple, + cnt[b].
__global__ __launch_bounds__(256) void k_pre(const float* __restrict__ Wk, ushort* __restrict__ wkt,
                                             const float* __restrict__ query, const float* __restrict__ Wq,
                                             const float* __restrict__ bq, float* __restrict__ qup,
                                             const int* __restrict__ mask, int* __restrict__ idxv,
                                             int* __restrict__ cntv){
  __shared__ float smem[1056];
  int bid = blockIdx.x;
  int t = threadIdx.x;
  if (bid >= 1152){
    int bb = bid - 1152;                 // batch
    const int* m = mask + (size_t)bb * LK;
    int* idxb = idxv + (size_t)bb * LK;
    int* ps = (int*)smem;
    int keep[8]; int c8 = 0;
#pragma unroll
    for (int u = 0; u < 8; ++u){
      keep[u] = (m[t*8 + u] == 0);
      c8 += keep[u];
    }
    ps[t] = c8; __syncthreads();
    for (int off = 1; off < 256; off <<= 1){
      int v = (t >= off) ? ps[t - off] : 0;
      __syncthreads();
      ps[t] += v;
      __syncthreads();
    }
    int pos = ps[t] - c8;                // exclusive prefix
    int tot = ps[255];
#pragma unroll
    for (int u = 0; u < 8; ++u){
      if (keep[u]) idxb[pos++] = t*8 + u;
    }
    int pad = ((tot + 127) >> 7) << 7;
    for (int p = tot + t; p < pad; p += 256) idxb[p] = 0;  // pad rows (stores masked out)
    if (t == 0) cntv[bb] = tot;
  } else if (bid < 1024){
    float (*tile)[33] = (float(*)[33])smem;
    int n0 = (bid & 31) * 32, k0 = (bid >> 5) * 32;
    int tx = t & 31, ty = t >> 5;
#pragma unroll
    for (int r = 0; r < 4; ++r)
      tile[ty + 8*r][tx] = Wk[(size_t)(k0 + ty + 8*r) * DM + n0 + tx];
    __syncthreads();
#pragma unroll
    for (int r = 0; r < 4; ++r){
      int n = ty + 8*r;
      wkt[(size_t)(n0 + n) * DM + k0 + tx] = f2bf(tile[tx][n]);
    }
  } else {
    int bb = bid - 1024;
    int b = bb >> 2, nc = bb & 3;
    float* q = smem;
#pragma unroll
    for (int j = 0; j < 4; ++j) q[j*256 + t] = query[(size_t)b*DM + j*256 + t];
    __syncthreads();
    int n = nc*256 + t;
    float acc = bq[n];
#pragma unroll 16
    for (int k = 0; k < DM; ++k) acc += q[k] * Wq[(size_t)k*DM + n];
    qup[(size_t)b*DM + n] = acc;
  }
}

// ---- K2 (R16-proven): v14 schedule + mask-compacted rows. 128x256 tile, 4 waves,
// wave tile 128x64 (acc[8][4] = 128 AGPR -> 2 waves/SIMD register floor; unified
// VGPR/AGPR file makes 3 blocks/CU infeasible at this tile — R17/R18 measured).
// B double-buffered, involution swizzle (conflict-free verified), T1 XCD grouping.
__global__ __launch_bounds__(256, 2) void k_gemm(
    const float* __restrict__ key, const ushort* __restrict__ wkt,
    const float* __restrict__ qup, const float* __restrict__ bk,
    const float* __restrict__ wsc, float* __restrict__ scores,
    const int* __restrict__ idxv, const int* __restrict__ cntv)
{
  __shared__ ushort ldsA[128*64];      // 16 KB (swizzled image)
  __shared__ ushort ldsB0[256*64];     // 32 KB
  __shared__ ushort ldsB1[256*64];     // 32 KB
  const int tid  = threadIdx.x;
  const int lane = tid & 63;
  const int wc   = tid >> 6;           // wave = col group 0..3 (one head each)
  const int l15  = lane & 15, l16 = lane >> 4;

  const int bid = blockIdx.x;          // grid 2048
  const int xcd = bid & 7;
  const int j   = bid >> 3;            // 0..255
  const int ct4 = j & 3;               // 256-col tile (4 heads)
  const int rb  = xcd * 64 + (j >> 2); // row panel 0..511
  const int b     = rb >> 4;
  const int panel = rb & 15;

  const int cnt = cntv[b];
  if (panel * 128 >= cnt) return;      // compacted panel count ~8-9 of 16
  const int* idxb = idxv + (size_t)b * LK;

  const int rlo = tid >> 3;            // 0..31
  const int g8  = rlo & 7;
  const int sk8 = (tid & 7) ^ g8;      // involution: source slot == written-image slot
  const ushort* bbase = wkt + ((size_t)ct4*256 + rlo) * DM + sk8*8;

  const float* akey[4];
#pragma unroll
  for (int c = 0; c < 4; ++c){
    int rowc = panel*128 + rlo + c*32;
    akey[c] = key + ((size_t)b * LK + idxb[rowc]) * DM + sk8*8;
  }

  float qbc[4], wm2[4], wsum = 0.f;
#pragma unroll
  for (int ni = 0; ni < 4; ++ni){
    int n = ct4*256 + wc*64 + ni*16 + l15;
    float w = wsc[ni*16 + l15];
    qbc[ni] = (qup[(size_t)b*DM + n] + bk[n]) * C2LOG2E;
    wm2[ni] = -2.f * w;
    wsum   += w;
  }

  f32x4 acc[8][4];
#pragma unroll
  for (int mi = 0; mi < 8; ++mi)
#pragma unroll
    for (int ni = 0; ni < 4; ++ni) acc[mi][ni] = (f32x4){0.f,0.f,0.f,0.f};

  const int sw = (l15 & 7) << 4;       // read-side XOR (row&7)<<4

  short8 sa[4];
#pragma unroll
  for (int c = 0; c < 4; ++c){
    const float* ap = akey[c];
    f32x4 x0 = *(const f32x4*)ap, x1 = *(const f32x4*)(ap + 4);
    sa[c] = pack8(x0, x1);
  }
#pragma unroll
  for (int c = 0; c < 8; ++c)
    gll16(bbase + (size_t)c*32*DM, (char*)ldsB0 + (c*256 + tid)*16);

  for (int kt = 0; kt < 16; ++kt){
#pragma unroll
    for (int c = 0; c < 4; ++c)
      *(short8*)((char*)ldsA + (c*256 + tid)*16) = sa[c];
    asm volatile("s_waitcnt vmcnt(0) lgkmcnt(0)" ::: "memory");
    __builtin_amdgcn_s_barrier();
    asm volatile("" ::: "memory");

    const char* Bc = (const char*)((kt & 1) ? ldsB1 : ldsB0);
    char*       Bn = (char*)((kt & 1) ? ldsB0 : ldsB1);
    f32x4 a0[4], a1[4];
    if (kt < 15){
#pragma unroll
      for (int c = 0; c < 8; ++c)
        gll16(bbase + (size_t)(kt+1)*64 + (size_t)c*32*DM, Bn + (c*256 + tid)*16);
#pragma unroll
      for (int c = 0; c < 4; ++c){
        const float* ap = akey[c] + (kt+1)*64;
        a0[c] = *(const f32x4*)ap; a1[c] = *(const f32x4*)(ap + 4);
      }
    }

#pragma unroll
    for (int kk = 0; kk < 2; ++kk){
      short8 af[8], bfr[4];
#pragma unroll
      for (int mi = 0; mi < 8; ++mi){
        int row = mi*16 + l15;
        af[mi] = *(const short8*)((const char*)ldsA + row*128 + ((kk*64 + l16*16) ^ sw));
      }
#pragma unroll
      for (int ni = 0; ni < 4; ++ni){
        int col = wc*64 + ni*16 + l15;
        bfr[ni] = *(const short8*)(Bc + col*128 + ((kk*64 + l16*16) ^ sw));
      }
      __builtin_amdgcn_s_setprio(1);
#pragma unroll
      for (int mi = 0; mi < 8; ++mi)
#pragma unroll
        for (int ni = 0; ni < 4; ++ni)
          acc[mi][ni] = __builtin_amdgcn_mfma_f32_16x16x32_bf16(af[mi], bfr[ni], acc[mi][ni], 0, 0, 0);
      __builtin_amdgcn_s_setprio(0);
    }

    if (kt < 15){
#pragma unroll
      for (int c = 0; c < 4; ++c)
        sa[c] = pack8(a0[c], a1[c]);
    }
    __builtin_amdgcn_s_barrier();
    asm volatile("" ::: "memory");
  }

  const size_t srow = (size_t)(b*NH + ct4*4 + wc) * LK;
#pragma unroll
  for (int mi = 0; mi < 8; ++mi){
    f32x4 s = {wsum, wsum, wsum, wsum};
#pragma unroll
    for (int ni = 0; ni < 4; ++ni)
#pragma unroll
      for (int r = 0; r < 4; ++r){
        float a  = fmaf(acc[mi][ni][r], C2LOG2E, qbc[ni]);
        float e  = __builtin_amdgcn_exp2f(a);
        float rc = __builtin_amdgcn_rcpf(e + 1.f);
        s[r] = fmaf(wm2[ni], rc, s[r]);
      }
#pragma unroll
    for (int r = 0; r < 4; ++r){
      float v = s[r];
      v += __shfl_xor(v, 1);
      v += __shfl_xor(v, 2);
      v += __shfl_xor(v, 4);
      v += __shfl_xor(v, 8);
      s[r] = v;
    }
    if (l15 == 0){
      int rowc0 = panel*128 + mi*16 + l16*4;
#pragma unroll
      for (int r = 0; r < 4; ++r){
        int rowc = rowc0 + r;
        if (rowc < cnt) scores[srow + idxb[rowc]] = s[r];
      }
    }
  }
}

// ---- K3 fused: masked softmax (attn output) + compacted context slice.
__global__ __launch_bounds__(256) void k_smctx(const float* __restrict__ scr, const int* __restrict__ mask,
                                               const float* __restrict__ value, float* __restrict__ attn,
                                               float* __restrict__ ctxbuf,
                                               const int* __restrict__ idxv, const int* __restrict__ cntv){
  __shared__ float red[8];
  __shared__ float sm[LK];
  const int bh = blockIdx.x;
  const int b = bh >> 4, h = bh & 15;
  const float* s = scr + (size_t)bh * LK;
  const int*   m = mask + (size_t)b * LK;
  float*       a = attn + (size_t)bh * LK;
  const int t = threadIdx.x;

  float sv[8]; int mv[8];
  float lmax = -1e30f;
#pragma unroll
  for (int j = 0; j < 8; ++j){
    int i = j*256 + t;
    sv[j] = s[i]; mv[j] = m[i];
    if (!mv[j]) lmax = fmaxf(lmax, sv[j]);
  }
#pragma unroll
  for (int off = 32; off >= 1; off >>= 1) lmax = fmaxf(lmax, __shfl_xor(lmax, off));
  if ((t & 63) == 0) red[t >> 6] = lmax;
  __syncthreads();
  lmax = fmaxf(fmaxf(red[0], red[1]), fmaxf(red[2], red[3]));

  float ev[8]; float lsum = 0.f;
#pragma unroll
  for (int j = 0; j < 8; ++j){
    ev[j] = mv[j] ? 0.f : __expf(sv[j] - lmax);
    lsum += ev[j];
  }
#pragma unroll
  for (int off = 32; off >= 1; off >>= 1) lsum += __shfl_xor(lsum, off);
  if ((t & 63) == 0) red[4 + (t >> 6)] = lsum;
  __syncthreads();
  lsum = red[4] + red[5] + red[6] + red[7];
  float inv = 1.f / lsum;
#pragma unroll
  for (int j = 0; j < 8; ++j){
    float w = ev[j] * inv;
    a[j*256 + t]  = w;
    sm[j*256 + t] = w;
  }
  __syncthreads();

  // compacted ctx: group w = t>>5 handles rows [p0,p1) of the idx list;
  // col pair c2 = (t&31)*2 (float2 = 8 B/lane).
  const int cnt = cntv[b];
  const int* idxb = idxv + (size_t)b * LK;
  const int c2 = (t & 31) * 2, w = t >> 5;
  const int per = (cnt + 7) >> 3;
  const int p0 = w * per;
  const int p1 = min(p0 + per, cnt);
  const float* vbase = value + (size_t)b*LK*DM + h*64 + c2;
  float px = 0.f, py = 0.f;
#pragma unroll 2
  for (int p = p0; p < p1; ++p){
    int l = idxb[p];
    float wgt = sm[l];
    float2 v = *(const float2*)(vbase + (size_t)l*DM);
    px = fmaf(wgt, v.x, px); py = fmaf(wgt, v.y, py);
  }
  float2 tot = make_float2(px, py);
  __syncthreads();                 // all reads of sm done
  *(float2*)&sm[w*64 + c2] = tot;  // 8 partials per col
  __syncthreads();
  if (t < 64){
    float r = 0.f;
#pragma unroll
    for (int g = 0; g < 8; ++g) r += sm[g*64 + t];
    ctxbuf[(size_t)b*DM + h*64 + t] = r;
  }
}

// ---- K6: output = context @ Wf + bf (output #1)
__global__ __launch_bounds__(256) void k_out(const float* __restrict__ ctxbuf, const float* __restrict__ Wf,
                                             const float* __restrict__ bfv, float* __restrict__ out){
  __shared__ float ctx[DM];
  int b = blockIdx.x >> 2, nc = blockIdx.x & 3;
  int t = threadIdx.x;
#pragma unroll
  for (int j = 0; j < 4; ++j)
    ctx[j*256 + t] = ctxbuf[(size_t)b*DM + j*256 + t];
  __syncthreads();
  int n = nc*256 + t;
  float acc = bfv[n];
#pragma unroll 16
  for (int k = 0; k < DM; ++k) acc += ctx[k] * Wf[(size_t)k*DM + n];
  out[(size_t)b*DM + n] = acc;
}

extern "C" void kernel_launch(void* const* d_in, const int* in_sizes, int n_in,
                              void* d_out, int out_size, void* d_ws, size_t ws_size,
                              hipStream_t stream){
  (void)in_sizes; (void)n_in; (void)out_size; (void)ws_size;
  const float* key   = (const float*)d_in[0];
  const float* value = (const float*)d_in[1];
  const float* query = (const float*)d_in[2];
  const int*   mask  = (const int*)d_in[3];
  const float* Wk    = (const float*)d_in[4];
  const float* bk    = (const float*)d_in[5];
  const float* Wq    = (const float*)d_in[6];
  const float* bq    = (const float*)d_in[7];
  const float* wsc   = (const float*)d_in[8];
  // d_in[9] = b_score: softmax-invariant, unused
  const float* Wf    = (const float*)d_in[10];
  const float* bfv   = (const float*)d_in[11];

  float* out0 = (float*)d_out;
  float* attn = out0 + (size_t)B_ * DM;   // [B,H,1,Lk] region

  char* ws = (char*)d_ws;
  ushort* wkt  = (ushort*)(ws);                                       // 2 MB
  float*  qup  = (float*)(ws + (2u<<20));                             // 128 KB
  float*  scr  = (float*)(ws + (2u<<20) + (128u<<10));                // 4 MB
  float*  ctxb = (float*)(ws + (2u<<20) + (128u<<10) + (4u<<20));     // 128 KB
  int*    idxv = (int*)  (ws + (2u<<20) + (256u<<10) + (4u<<20));     // 256 KB
  int*    cntv = (int*)  (ws + (2u<<20) + (512u<<10) + (4u<<20));     // 128 B

  k_pre<<<1184, 256, 0, stream>>>(Wk, wkt, query, Wq, bq, qup, mask, idxv, cntv);
  k_gemm<<<2048, 256, 0, stream>>>(key, wkt, qup, bk, wsc, scr, idxv, cntv);
  k_smctx<<<512, 256, 0, stream>>>(scr, mask, value, attn, ctxb, idxv, cntv);
  k_out<<<128, 256, 0, stream>>>(ctxb, Wf, bfv, out0);
}